// Round 8
// baseline (18149.251 us; speedup 1.0000x reference)
//
#include <hip/hip_runtime.h>
#include <hip/hip_bf16.h>

// LatticeLSTM on MI355X — Round 7 (2nd resubmit; 7 consecutive infra failures,
// no data yet): hang-proof XCD-local (L2-scope) communication.
// Theory: grid (x=seq, y=wg) -> linear id % 8 == seq -> all 32 WGs of a seq
// share one XCD; sc0 (SE-scope) pub/poll coherence-points at the XCD L2
// (~250cy RT) instead of sc1/LLC (~700-1000cy). Two such trips/step dominated
// the R5 baseline (5607us, VALUBusy 25%).
// Robustness (worst case is a measurable regression, never a hang):
//   * DUAL-PUBLISH: fast mode writes BOTH sc0 and sc1 buffers (sc1 store is
//     fire-and-forget). Slow path is always valid.
//   * BOUNDED fast spin (64 iters) then dual-check loop (sc1 + sc0 each iter):
//     progress guaranteed by the sc1 path even if sc0 visibility were broken.
//   * runtime co-location verdict via s_getreg(HW_REG_XCC_ID) over sc1; verdict
//     symmetric -> all WGs of a seq agree fast/slow. Non-co-located -> R5 path.
// Step layout (2 syncthreads/step, parity-double-buffered LDS):
//   A1 matvecs(h(t-1),x) | A2 poll pend | S1 | A3 alpha+gates, publish h
//   B2 stage x(t+1) + xw matvecs + reduce + poll h(t) | S2 | B3 word gates, publish pend
// pmask is data-independent: m0=(t>=1), m1=(t>=3); c_plain only at t=0.
// Progress needs all 256 WGs co-resident (1 WG/CU; LDS ~11KB, VGPR<256).

#define Bq 8
#define Tq 1024
#define DCq 128
#define Hq 512
#define NWG 32
#define NTHR 256
#define SPINF 64

typedef unsigned long long u64;

// ws byte offsets
#define HPUBF_OFF 0u         // u64 h_pub_fast[8][2][512]   = 65536
#define PENDF_OFF 65536u     // u64 pend_fast[8][4][2][512] = 262144
#define HPUBS_OFF 327680u    // u64 h_pub_slow[8][2][512]   = 65536
#define PENDS_OFF 393216u    // u64 pend_slow[8][4][2][512] = 262144
#define XCD_OFF   655360u    // u64 xcd[8][32]              = 2048
#define WIHT_OFF  657408u    // bf16 [1536][128]
#define WHHT_OFF  1050624u   // bf16 [1536][512]
#define AWIHT_OFF 2623488u   // bf16 [512][128]
#define AWHHT_OFF 2754560u   // bf16 [512][512]
#define WWIHT_OFF 3278848u   // bf16 [1536][128]
#define WWHHT_OFF 3672064u   // bf16 [1536][512]  (end 5244928)

__device__ __forceinline__ float bflo(unsigned u){ return __uint_as_float(u << 16); }
__device__ __forceinline__ float bfhi(unsigned u){ return __uint_as_float(u & 0xffff0000u); }
__device__ __forceinline__ float sigm(float x){ return 1.0f / (1.0f + __expf(-x)); }

__device__ __forceinline__ void fma4(float& acc, uint2 w, float4 v){
  acc = fmaf(bflo(w.x), v.x, acc);
  acc = fmaf(bfhi(w.x), v.y, acc);
  acc = fmaf(bflo(w.y), v.z, acc);
  acc = fmaf(bfhi(w.y), v.w, acc);
}

__device__ __forceinline__ float red16(float x){
  x += __shfl_xor(x, 8, 16);
  x += __shfl_xor(x, 4, 16);
  x += __shfl_xor(x, 2, 16);
  x += __shfl_xor(x, 1, 16);
  return x;
}

__device__ __forceinline__ u64 pack64(float v, unsigned gen){
  return ((u64)gen << 32) | (u64)__float_as_uint(v);
}
__device__ __forceinline__ void pub64(u64* p, u64 v){
  __hip_atomic_store(p, v, __ATOMIC_RELAXED, __HIP_MEMORY_SCOPE_AGENT);
}
__device__ __forceinline__ u64 ld64(const u64* p){
  return __hip_atomic_load(p, __ATOMIC_RELAXED, __HIP_MEMORY_SCOPE_AGENT);
}
__device__ __forceinline__ unsigned genof(u64 v){ return (unsigned)(v >> 32); }
__device__ __forceinline__ float valof(u64 v){ return __uint_as_float((unsigned)v); }

// ---- XCD-local (SE-scope) ops: bypass L1, coherence-point at the XCD L2 ----
__device__ __forceinline__ void st64_sc0(u64* p, u64 v){
  asm volatile("global_store_dwordx2 %0, %1, off sc0" :: "v"(p), "v"(v) : "memory");
}
__device__ __forceinline__ void ld2_sc0(const u64* p0, const u64* p1, u64& a, u64& b){
  asm volatile("global_load_dwordx2 %0, %2, off sc0\n\t"
               "global_load_dwordx2 %1, %3, off sc0\n\t"
               "s_waitcnt vmcnt(0)"
               : "=&v"(a), "=&v"(b)
               : "v"(p0), "v"(p1)
               : "memory");
}
__device__ __forceinline__ void ld4_sc0(const u64* p0, const u64* p1,
                                        const u64* p2, const u64* p3,
                                        u64& a, u64& b, u64& c, u64& d){
  asm volatile("global_load_dwordx2 %0, %4, off sc0\n\t"
               "global_load_dwordx2 %1, %5, off sc0\n\t"
               "global_load_dwordx2 %2, %6, off sc0\n\t"
               "global_load_dwordx2 %3, %7, off sc0\n\t"
               "s_waitcnt vmcnt(0)"
               : "=&v"(a), "=&v"(b), "=&v"(c), "=&v"(d)
               : "v"(p0), "v"(p1), "v"(p2), "v"(p3)
               : "memory");
}

// src [K][N] fp32 -> dst [N][K] bf16 (transpose + convert). K is pow2.
__global__ void transpose_bf16(const float* __restrict__ src, __hip_bfloat16* __restrict__ dst,
                               int kshift, int total, int N){
  const int K = 1 << kshift;
  for (int idx = blockIdx.x * blockDim.x + threadIdx.x; idx < total;
       idx += gridDim.x * blockDim.x){
    int n = idx >> kshift;
    int k = idx & (K - 1);
    dst[idx] = __float2bfloat16(src[(size_t)k * N + n]);
  }
}

__global__ void __launch_bounds__(NTHR, 1)
lattice_main(const float* __restrict__ char_emb,
             const int*   __restrict__ word_ids,
             const float* __restrict__ sense_table,
             const float* __restrict__ bias_b,
             const float* __restrict__ bias_ab,
             const float* __restrict__ bias_wb,
             unsigned char* __restrict__ ws,
             float* __restrict__ out)
{
  const int seq  = blockIdx.x;
  const int wg   = blockIdx.y;
  const int tid  = threadIdx.x;
  const int grp  = tid >> 4;
  const int lane = tid & 15;
  const int J    = wg * 16 + grp;               // owned H column
  const int i0   = tid * 2, i1 = tid * 2 + 1;   // poll columns for this thread

  u64* hpubf = (u64*)(ws + HPUBF_OFF) + (size_t)seq * 2 * Hq;      // [parity][col]
  u64* hpubs = (u64*)(ws + HPUBS_OFF) + (size_t)seq * 2 * Hq;
  u64* pndf  = (u64*)(ws + PENDF_OFF) + (size_t)seq * 4 * 2 * Hq;  // [slot][k][col]
  u64* pnds  = (u64*)(ws + PENDS_OFF) + (size_t)seq * 4 * 2 * Hq;

  const uint2* w_ihT  = (const uint2*)(ws + WIHT_OFF);
  const uint2* w_hhT  = (const uint2*)(ws + WHHT_OFF);
  const uint2* aw_ihT = (const uint2*)(ws + AWIHT_OFF);
  const uint2* aw_hhT = (const uint2*)(ws + AWHHT_OFF);
  const uint2* ww_ihT = (const uint2*)(ws + WWIHT_OFF);
  const uint2* ww_hhT = (const uint2*)(ws + WWHHT_OFF);

  // ---- hoist ALL weights into registers (addresses are t-invariant) ----
  uint2 Rwhh_i[8], Rwhh_o[8], Rwhh_g[8], Rawhh[8];
  uint2 Rwwh_f[8], Rwwh_i[8], Rwwh_g[8];
  uint2 Rwih_i[2], Rwih_o[2], Rwih_g[2], Rawih[2];
  uint2 Rwwi_f[2], Rwwi_i[2], Rwwi_g[2];
  {
    const uint2* whh_i = w_hhT  + (size_t)(0*Hq + J) * 128;
    const uint2* whh_o = w_hhT  + (size_t)(1*Hq + J) * 128;
    const uint2* whh_g = w_hhT  + (size_t)(2*Hq + J) * 128;
    const uint2* awhh  = aw_hhT + (size_t)J * 128;
    const uint2* wwh_f = ww_hhT + (size_t)(0*Hq + J) * 128;
    const uint2* wwh_i = ww_hhT + (size_t)(1*Hq + J) * 128;
    const uint2* wwh_g = ww_hhT + (size_t)(2*Hq + J) * 128;
#pragma unroll
    for (int it = 0; it < 8; ++it){
      const int q = it * 16 + lane;
      Rwhh_i[it] = whh_i[q];  Rwhh_o[it] = whh_o[q];  Rwhh_g[it] = whh_g[q];
      Rawhh[it]  = awhh[q];
      Rwwh_f[it] = wwh_f[q];  Rwwh_i[it] = wwh_i[q];  Rwwh_g[it] = wwh_g[q];
    }
    const uint2* wih_i = w_ihT  + (size_t)(0*Hq + J) * 32;
    const uint2* wih_o = w_ihT  + (size_t)(1*Hq + J) * 32;
    const uint2* wih_g = w_ihT  + (size_t)(2*Hq + J) * 32;
    const uint2* awih  = aw_ihT + (size_t)J * 32;
    const uint2* wwi_f = ww_ihT + (size_t)(0*Hq + J) * 32;
    const uint2* wwi_i = ww_ihT + (size_t)(1*Hq + J) * 32;
    const uint2* wwi_g = ww_ihT + (size_t)(2*Hq + J) * 32;
#pragma unroll
    for (int it = 0; it < 2; ++it){
      const int q = it * 16 + lane;
      Rwih_i[it] = wih_i[q];  Rwih_o[it] = wih_o[q];  Rwih_g[it] = wih_g[q];
      Rawih[it]  = awih[q];
      Rwwi_f[it] = wwi_f[q];  Rwwi_i[it] = wwi_i[q];  Rwwi_g[it] = wwi_g[q];
    }
  }

  const float b_i  = bias_b[J], b_o = bias_b[Hq + J], b_g = bias_b[2*Hq + J];
  const float ab_J = bias_ab[J];
  const float wb_f = bias_wb[J], wb_i = bias_wb[Hq + J], wb_g = bias_wb[2*Hq + J];

  float* out_h = out + (size_t)seq * Tq * Hq;            // hs block
  float* out_c = out + ((size_t)Bq + seq) * Tq * Hq;     // cs block

  __shared__ __align__(16) float shH[2][Hq];      // h by parity: shH[t&1] = h(t)
  __shared__ __align__(16) float sh_p0[Hq];
  __shared__ __align__(16) float sh_p1[Hq];
  __shared__ __align__(16) float shx[2][DCq];     // x(t) in shx[t&1]
  __shared__ __align__(16) float shxw0[2][DCq];   // xw(t) in shxw*[t&1]
  __shared__ __align__(16) float shxw1[2][DCq];
  __shared__ int sh_fast;

  // ---- pre-loop staging: zeros + x(0), xw(0) ----
  shH[0][i0] = 0.f; shH[0][i1] = 0.f;
  shH[1][i0] = 0.f; shH[1][i1] = 0.f;
  sh_p0[i0] = 0.f; sh_p0[i1] = 0.f;
  sh_p1[i0] = 0.f; sh_p1[i1] = 0.f;
  if (tid < DCq){
    shx[0][tid] = char_emb[((size_t)seq * Tq + 0) * DCq + tid];
  } else {
    const int k = tid - DCq;
    const int w0 = word_ids[(size_t)seq * Tq * 2 + 0];
    const int w1 = word_ids[(size_t)seq * Tq * 2 + 1];
    shxw0[0][k] = sense_table[(size_t)w0 * DCq + k];
    shxw1[0][k] = sense_table[(size_t)w1 * DCq + k];
  }

  // ---- co-location verdict: all 32 WGs of this seq on one XCD? ----
  // Exchanged via the sc1 (always-correct) path. Verdict is symmetric, hence
  // identical across the seq's WGs: producers+consumers agree on the path.
  {
    unsigned myxcc;
    asm volatile("s_getreg_b32 %0, hwreg(HW_REG_XCC_ID)" : "=s"(myxcc));
    u64* xcdb = (u64*)(ws + XCD_OFF) + (size_t)seq * NWG;
    if (tid == 0){
      pub64(&xcdb[wg], ((u64)1 << 32) | (u64)myxcc);
    }
    if (tid < 64){
      bool ok = true;
      if (tid < NWG){
        u64 v;
        do { v = ld64(&xcdb[tid]); } while (genof(v) == 0);
        ok = ((unsigned)v == myxcc);
      }
      const unsigned long long m = __ballot(ok);
      if (tid == 0) sh_fast = (m == ~0ull) ? 1 : 0;
    }
  }
  __syncthreads();
  const bool fast = (sh_fast != 0);

  for (int t = 0; t < Tq; ++t){
    const int par = t & 1;
    const float* hprev = shH[par ^ 1];     // h(t-1)

    // ---- A1: i/o/g/xa matvecs (pend NOT needed) ----
    float a_i = 0.f, a_o = 0.f, a_g = 0.f, a_xa = 0.f;
#pragma unroll
    for (int it = 0; it < 8; ++it){
      const int k0 = it * 64 + lane * 4;
      float4 hv = *(const float4*)(hprev + k0);
      fma4(a_i, Rwhh_i[it], hv);
      fma4(a_o, Rwhh_o[it], hv);
      fma4(a_g, Rwhh_g[it], hv);
    }
#pragma unroll
    for (int it = 0; it < 2; ++it){
      const int k0 = it * 64 + lane * 4;
      float4 xv = *(const float4*)(shx[par] + k0);
      fma4(a_i,  Rwih_i[it], xv);
      fma4(a_o,  Rwih_o[it], xv);
      fma4(a_g,  Rwih_g[it], xv);
      fma4(a_xa, Rawih[it],  xv);
    }

    // ---- A2: poll pend for step t (usually already visible) ----
    if (t >= 3){
      const unsigned tg0 = (unsigned)t, tg1 = (unsigned)(t - 2);
      const u64* f0 = pndf + ((size_t)(t & 3) * 2 + 0) * Hq;
      const u64* f1 = pndf + ((size_t)(t & 3) * 2 + 1) * Hq;
      const u64* s0 = pnds + ((size_t)(t & 3) * 2 + 0) * Hq;
      const u64* s1 = pnds + ((size_t)(t & 3) * 2 + 1) * Hq;
      u64 a, b, c, d;
      bool done = false;
      if (fast){
        for (int s = 0; s < SPINF; ++s){
          ld4_sc0(f0 + i0, f0 + i1, f1 + i0, f1 + i1, a, b, c, d);
          if (genof(a) >= tg0 && genof(b) >= tg0 &&
              genof(c) >= tg1 && genof(d) >= tg1){ done = true; break; }
        }
      }
      if (!done){
        for (;;){
          a = ld64(s0 + i0); b = ld64(s0 + i1);
          c = ld64(s1 + i0); d = ld64(s1 + i1);
          if (genof(a) >= tg0 && genof(b) >= tg0 &&
              genof(c) >= tg1 && genof(d) >= tg1) break;
          if (fast){
            ld4_sc0(f0 + i0, f0 + i1, f1 + i0, f1 + i1, a, b, c, d);
            if (genof(a) >= tg0 && genof(b) >= tg0 &&
                genof(c) >= tg1 && genof(d) >= tg1) break;
          }
        }
      }
      sh_p0[i0] = valof(a); sh_p0[i1] = valof(b);
      sh_p1[i0] = valof(c); sh_p1[i1] = valof(d);
    } else if (t >= 1){
      const unsigned tg0 = (unsigned)t;
      const u64* f0 = pndf + ((size_t)(t & 3) * 2 + 0) * Hq;
      const u64* s0 = pnds + ((size_t)(t & 3) * 2 + 0) * Hq;
      u64 a, b;
      bool done = false;
      if (fast){
        for (int s = 0; s < SPINF; ++s){
          ld2_sc0(f0 + i0, f0 + i1, a, b);
          if (genof(a) >= tg0 && genof(b) >= tg0){ done = true; break; }
        }
      }
      if (!done){
        for (;;){
          a = ld64(s0 + i0); b = ld64(s0 + i1);
          if (genof(a) >= tg0 && genof(b) >= tg0) break;
          if (fast){
            ld2_sc0(f0 + i0, f0 + i1, a, b);
            if (genof(a) >= tg0 && genof(b) >= tg0) break;
          }
        }
      }
      sh_p0[i0] = valof(a); sh_p0[i1] = valof(b);
      // sh_p1 stays zero (mask m1=0 for t<3)
    }
    __syncthreads();   // S1

    // ---- A3: alpha matvecs + gates ----
    float a_p0 = 0.f, a_p1 = 0.f;
#pragma unroll
    for (int it = 0; it < 8; ++it){
      const int k0 = it * 64 + lane * 4;
      float4 p0v = *(const float4*)(sh_p0 + k0);
      float4 p1v = *(const float4*)(sh_p1 + k0);
      fma4(a_p0, Rawhh[it], p0v);
      fma4(a_p1, Rawhh[it], p1v);
    }
    a_i  = red16(a_i);  a_o  = red16(a_o);  a_g  = red16(a_g);
    a_xa = red16(a_xa); a_p0 = red16(a_p0); a_p1 = red16(a_p1);

    const float gi = sigm(a_i + b_i);
    const float go = sigm(a_o + b_o);
    const float gg = tanhf(a_g + b_g);
    float c1;
    if (t == 0){
      c1 = gi * gg;                       // c_plain with c=0
    } else {
      const float base = a_xa + ab_J;
      const float ea0 = __expf(sigm(base + a_p0));   // m0=1 for t>=1
      const float ei  = __expf(gi);
      float num = ei * gg + ea0 * sh_p0[J];
      float den = ei + ea0;
      if (t >= 3){                                    // m1=1 for t>=3
        const float ea1 = __expf(sigm(base + a_p1));
        num += ea1 * sh_p1[J];
        den += ea1;
      }
      c1 = num / den;
    }
    const float h1 = go * tanhf(c1);
    if (lane == 0){
      const u64 pk = pack64(h1, (unsigned)(t + 1));
      if (fast) st64_sc0(hpubf + (size_t)par * Hq + J, pk);   // fast copy (sc0)
      pub64(hpubs + (size_t)par * Hq + J, pk);                // always: slow copy (sc1)
      out_h[(size_t)t * Hq + J] = h1;
      out_c[(size_t)t * Hq + J] = c1;
    }

    // ---- B2: stage x/xw(t+1) + h-independent word matvecs + poll h(t) ----
    float x_f0 = 0.f, x_i0 = 0.f, x_g0 = 0.f, x_f1 = 0.f, x_i1 = 0.f, x_g1 = 0.f;
    {
      const int tn = (t + 1 < Tq) ? t + 1 : t;
      if (tid < DCq){
        shx[par ^ 1][tid] = char_emb[((size_t)seq * Tq + tn) * DCq + tid];
      } else {
        const int k = tid - DCq;
        const int w0 = word_ids[((size_t)seq * Tq + tn) * 2 + 0];
        const int w1 = word_ids[((size_t)seq * Tq + tn) * 2 + 1];
        shxw0[par ^ 1][k] = sense_table[(size_t)w0 * DCq + k];
        shxw1[par ^ 1][k] = sense_table[(size_t)w1 * DCq + k];
      }
      // h-independent parts of the word gates (reads shxw*[par], written at t-1)
#pragma unroll
      for (int it = 0; it < 2; ++it){
        const int k0 = it * 64 + lane * 4;
        float4 x0 = *(const float4*)(shxw0[par] + k0);
        float4 x1 = *(const float4*)(shxw1[par] + k0);
        fma4(x_f0, Rwwi_f[it], x0);  fma4(x_f1, Rwwi_f[it], x1);
        fma4(x_i0, Rwwi_i[it], x0);  fma4(x_i1, Rwwi_i[it], x1);
        fma4(x_g0, Rwwi_g[it], x0);  fma4(x_g1, Rwwi_g[it], x1);
      }
      x_f0 = red16(x_f0); x_i0 = red16(x_i0); x_g0 = red16(x_g0);
      x_f1 = red16(x_f1); x_i1 = red16(x_i1); x_g1 = red16(x_g1);

      // poll full h(t) — the ONE exposed round trip
      const unsigned tg = (unsigned)(t + 1);
      const u64* hf = hpubf + (size_t)par * Hq;
      const u64* hs = hpubs + (size_t)par * Hq;
      u64 a, b;
      bool done = false;
      if (fast){
        for (int s = 0; s < SPINF; ++s){
          ld2_sc0(hf + i0, hf + i1, a, b);
          if (genof(a) >= tg && genof(b) >= tg){ done = true; break; }
        }
      }
      if (!done){
        for (;;){
          a = ld64(hs + i0); b = ld64(hs + i1);
          if (genof(a) >= tg && genof(b) >= tg) break;
          if (fast){
            ld2_sc0(hf + i0, hf + i1, a, b);
            if (genof(a) >= tg && genof(b) >= tg) break;
          }
        }
      }
      shH[par][i0] = valof(a); shH[par][i1] = valof(b);
    }
    __syncthreads();   // S2

    // ---- B3: h-dependent word gates ----
    float r_f = 0.f, r_i = 0.f, r_g = 0.f;
#pragma unroll
    for (int it = 0; it < 8; ++it){
      const int k0 = it * 64 + lane * 4;
      float4 hv = *(const float4*)(shH[par] + k0);
      fma4(r_f, Rwwh_f[it], hv);
      fma4(r_i, Rwwh_i[it], hv);
      fma4(r_g, Rwwh_g[it], hv);
    }
    r_f = red16(r_f);  r_i = red16(r_i);  r_g = red16(r_g);

    if (lane == 0){
      const float f0  = sigm(r_f + x_f0 + wb_f);
      const float iw0 = sigm(r_i + x_i0 + wb_i);
      const float g0  = tanhf(r_g + x_g0 + wb_g);
      const float cw0 = f0 * c1 + iw0 * g0;
      const float f1  = sigm(r_f + x_f1 + wb_f);
      const float iw1 = sigm(r_i + x_i1 + wb_i);
      const float g1  = tanhf(r_g + x_g1 + wb_g);
      const float cw1 = f1 * c1 + iw1 * g1;
      // gen = production step + 1; consumers poll p0>=t_c, p1>=t_c-2
      const u64 k0 = pack64(cw0, (unsigned)(t + 1));
      const u64 k1 = pack64(cw1, (unsigned)(t + 1));
      if (fast){
        st64_sc0(pndf + ((size_t)((t + 1) & 3) * 2 + 0) * Hq + J, k0);
        st64_sc0(pndf + ((size_t)((t + 3) & 3) * 2 + 1) * Hq + J, k1);
      }
      // always: slow copies (sc1) — guarantees consumer progress
      pub64(pnds + ((size_t)((t + 1) & 3) * 2 + 0) * Hq + J, k0);
      pub64(pnds + ((size_t)((t + 3) & 3) * 2 + 1) * Hq + J, k1);
    }
    // no barrier here: next A1 touches only shH[par^1]/shx[par^1] (disjoint),
    // next A2 LDS writes are fenced by S1; pend LDS buffers re-written only
    // after S2 of this step (cross-thread ordering via S1/S2 chain).
  }
}

extern "C" void kernel_launch(void* const* d_in, const int* in_sizes, int n_in,
                              void* d_out, int out_size, void* d_ws, size_t ws_size,
                              hipStream_t stream){
  const float* char_emb = (const float*)d_in[0];
  const int*   word_ids = (const int*)d_in[1];
  const float* sense    = (const float*)d_in[2];
  const float* w_ih     = (const float*)d_in[3];
  const float* w_hh     = (const float*)d_in[4];
  const float* bb       = (const float*)d_in[5];
  const float* aw_ih    = (const float*)d_in[6];
  const float* aw_hh    = (const float*)d_in[7];
  const float* ab       = (const float*)d_in[8];
  const float* ww_ih    = (const float*)d_in[9];
  const float* ww_hh    = (const float*)d_in[10];
  const float* wb       = (const float*)d_in[11];
  unsigned char* ws = (unsigned char*)d_ws;
  float* out = (float*)d_out;

  // zero all generation words (h_pub/pend fast+slow + xcd exchange)
  hipMemsetAsync(ws, 0, WIHT_OFF, stream);

  // one-time (per launch) weight convert+transpose to bf16
  transpose_bf16<<<512, NTHR, 0, stream>>>(w_ih,  (__hip_bfloat16*)(ws + WIHT_OFF),  7, 128*1536, 1536);
  transpose_bf16<<<512, NTHR, 0, stream>>>(w_hh,  (__hip_bfloat16*)(ws + WHHT_OFF),  9, 512*1536, 1536);
  transpose_bf16<<<512, NTHR, 0, stream>>>(aw_ih, (__hip_bfloat16*)(ws + AWIHT_OFF), 7, 128*512,  512);
  transpose_bf16<<<512, NTHR, 0, stream>>>(aw_hh, (__hip_bfloat16*)(ws + AWHHT_OFF), 9, 512*512,  512);
  transpose_bf16<<<512, NTHR, 0, stream>>>(ww_ih, (__hip_bfloat16*)(ws + WWIHT_OFF), 7, 128*1536, 1536);
  transpose_bf16<<<512, NTHR, 0, stream>>>(ww_hh, (__hip_bfloat16*)(ws + WWHHT_OFF), 9, 512*1536, 1536);

  dim3 grid(Bq, NWG);   // x = seq (XCD-local: linear id % 8 == seq), y = wg slice
  lattice_main<<<grid, NTHR, 0, stream>>>(char_emb, word_ids, sense, bb, ab, wb, ws, out);
}

// Round 11
// 8245.062 us; speedup vs baseline: 2.2012x; 2.2012x over previous
//
#include <hip/hip_runtime.h>
#include <hip/hip_bf16.h>

// LatticeLSTM on MI355X — Round 9 (2nd resubmit; R9/R10 benches were
// acquisition timeouts): merged dual-scope polling (no timeouts).
// R8 post-mortem: R7's sc0-store fast path NEVER became visible to same-XCD
// sc0 loads (64-iter spins timed out every step: +12.3us/step, FETCH down to
// 70MB = L2-resident spinning). Co-location of a seq's 32 WGs on one XCD was
// CONFIRMED (else fallback ≡ R5's 5.6ms; we saw 18.1ms = timeout burn).
// This round removes the timeout structure entirely:
//   * every poll iteration issues FAST loads (sc0, from plain-stored L2 lines)
//     and SLOW loads (sc1/LLC) back-to-back, waits once, accepts either.
//     Worst-case latency == R5's sc1 iteration; best case = L2 visibility.
//   * fast publish is a PLAIN store (write-through to the local XCD L2 —
//     classic GLC-load producer/consumer idiom); sc1 copy always follows.
//   * no XCD check needed: protocol is correct under ANY placement.
//   * poll loads are 16B dwordx4 (i0,i1 contiguous) — half the requests.
//   * early issue: A2's slow loads issued before A1 (hidden under matvecs),
//     B2's slow loads issued before staging+xw matvecs.
// Step layout (2 syncthreads/step, parity-double-buffered LDS):
//   P0 early pend loads | A1 matvecs(h(t-1),x) | A2 check/poll pend | S1
//   A3 alpha+gates, publish h | B2 early h loads + stage x(t+1) + xw matvecs
//   + check/poll h(t) | S2 | B3 word gates, publish pend
// pmask is data-independent: m0=(t>=1), m1=(t>=3); c_plain only at t=0.
// Progress needs all 256 WGs co-resident (1 WG/CU; LDS ~11KB, VGPR<256).

#define Bq 8
#define Tq 1024
#define DCq 128
#define Hq 512
#define NWG 32
#define NTHR 256

typedef unsigned long long u64;
typedef __attribute__((ext_vector_type(4))) unsigned int u32x4;

// ws byte offsets
#define HPUBF_OFF 0u         // u64 h_pub_fast[8][2][512]   = 65536
#define PENDF_OFF 65536u     // u64 pend_fast[8][4][2][512] = 262144
#define HPUBS_OFF 327680u    // u64 h_pub_slow[8][2][512]   = 65536
#define PENDS_OFF 393216u    // u64 pend_slow[8][4][2][512] = 262144
#define WIHT_OFF  657408u    // bf16 [1536][128]
#define WHHT_OFF  1050624u   // bf16 [1536][512]
#define AWIHT_OFF 2623488u   // bf16 [512][128]
#define AWHHT_OFF 2754560u   // bf16 [512][512]
#define WWIHT_OFF 3278848u   // bf16 [1536][128]
#define WWHHT_OFF 3672064u   // bf16 [1536][512]  (end 5244928)

__device__ __forceinline__ float bflo(unsigned u){ return __uint_as_float(u << 16); }
__device__ __forceinline__ float bfhi(unsigned u){ return __uint_as_float(u & 0xffff0000u); }
__device__ __forceinline__ float sigm(float x){ return 1.0f / (1.0f + __expf(-x)); }

__device__ __forceinline__ void fma4(float& acc, uint2 w, float4 v){
  acc = fmaf(bflo(w.x), v.x, acc);
  acc = fmaf(bfhi(w.x), v.y, acc);
  acc = fmaf(bflo(w.y), v.z, acc);
  acc = fmaf(bfhi(w.y), v.w, acc);
}

__device__ __forceinline__ float red16(float x){
  x += __shfl_xor(x, 8, 16);
  x += __shfl_xor(x, 4, 16);
  x += __shfl_xor(x, 2, 16);
  x += __shfl_xor(x, 1, 16);
  return x;
}

__device__ __forceinline__ u64 pack64(float v, unsigned gen){
  return ((u64)gen << 32) | (u64)__float_as_uint(v);
}
__device__ __forceinline__ void pub64(u64* p, u64 v){
  __hip_atomic_store(p, v, __ATOMIC_RELAXED, __HIP_MEMORY_SCOPE_AGENT);
}
__device__ __forceinline__ u64 ld64(const u64* p){
  return __hip_atomic_load(p, __ATOMIC_RELAXED, __HIP_MEMORY_SCOPE_AGENT);
}
__device__ __forceinline__ unsigned genof(u64 v){ return (unsigned)(v >> 32); }

// Merged dual-scope poll loads. 16B per buffer (two adjacent u64 cells).
// u32x4 lanes: .x=val0 .y=gen0 .z=val1 .w=gen1 (little-endian dword pairs).
// Fast loads (sc0: bypass L1, read local XCD L2) issued first; slow loads
// (sc1: LLC coherence point) after; one vmcnt(0) — latency = max = slow RT.
__device__ __forceinline__ void duo_load(const u64* pf, const u64* ps,
                                         u32x4& f, u32x4& s){
  asm volatile("global_load_dwordx4 %0, %2, off sc0\n\t"
               "global_load_dwordx4 %1, %3, off sc1\n\t"
               "s_waitcnt vmcnt(0)"
               : "=&v"(f), "=&v"(s)
               : "v"(pf), "v"(ps)
               : "memory");
}
__device__ __forceinline__ void quad_load(const u64* pf0, const u64* pf1,
                                          const u64* ps0, const u64* ps1,
                                          u32x4& f0, u32x4& f1,
                                          u32x4& s0, u32x4& s1){
  asm volatile("global_load_dwordx4 %0, %4, off sc0\n\t"
               "global_load_dwordx4 %1, %5, off sc0\n\t"
               "global_load_dwordx4 %2, %6, off sc1\n\t"
               "global_load_dwordx4 %3, %7, off sc1\n\t"
               "s_waitcnt vmcnt(0)"
               : "=&v"(f0), "=&v"(f1), "=&v"(s0), "=&v"(s1)
               : "v"(pf0), "v"(pf1), "v"(ps0), "v"(ps1)
               : "memory");
}

// src [K][N] fp32 -> dst [N][K] bf16 (transpose + convert). K is pow2.
__global__ void transpose_bf16(const float* __restrict__ src, __hip_bfloat16* __restrict__ dst,
                               int kshift, int total, int N){
  const int K = 1 << kshift;
  for (int idx = blockIdx.x * blockDim.x + threadIdx.x; idx < total;
       idx += gridDim.x * blockDim.x){
    int n = idx >> kshift;
    int k = idx & (K - 1);
    dst[idx] = __float2bfloat16(src[(size_t)k * N + n]);
  }
}

__global__ void __launch_bounds__(NTHR, 1)
lattice_main(const float* __restrict__ char_emb,
             const int*   __restrict__ word_ids,
             const float* __restrict__ sense_table,
             const float* __restrict__ bias_b,
             const float* __restrict__ bias_ab,
             const float* __restrict__ bias_wb,
             unsigned char* __restrict__ ws,
             float* __restrict__ out)
{
  const int seq  = blockIdx.x;
  const int wg   = blockIdx.y;
  const int tid  = threadIdx.x;
  const int grp  = tid >> 4;
  const int lane = tid & 15;
  const int J    = wg * 16 + grp;               // owned H column
  const int i0   = tid * 2, i1 = tid * 2 + 1;   // poll columns (contiguous 16B)

  u64* hpubf = (u64*)(ws + HPUBF_OFF) + (size_t)seq * 2 * Hq;      // [parity][col]
  u64* hpubs = (u64*)(ws + HPUBS_OFF) + (size_t)seq * 2 * Hq;
  u64* pndf  = (u64*)(ws + PENDF_OFF) + (size_t)seq * 4 * 2 * Hq;  // [slot][k][col]
  u64* pnds  = (u64*)(ws + PENDS_OFF) + (size_t)seq * 4 * 2 * Hq;

  const uint2* w_ihT  = (const uint2*)(ws + WIHT_OFF);
  const uint2* w_hhT  = (const uint2*)(ws + WHHT_OFF);
  const uint2* aw_ihT = (const uint2*)(ws + AWIHT_OFF);
  const uint2* aw_hhT = (const uint2*)(ws + AWHHT_OFF);
  const uint2* ww_ihT = (const uint2*)(ws + WWIHT_OFF);
  const uint2* ww_hhT = (const uint2*)(ws + WWHHT_OFF);

  // ---- hoist ALL weights into registers (addresses are t-invariant) ----
  uint2 Rwhh_i[8], Rwhh_o[8], Rwhh_g[8], Rawhh[8];
  uint2 Rwwh_f[8], Rwwh_i[8], Rwwh_g[8];
  uint2 Rwih_i[2], Rwih_o[2], Rwih_g[2], Rawih[2];
  uint2 Rwwi_f[2], Rwwi_i[2], Rwwi_g[2];
  {
    const uint2* whh_i = w_hhT  + (size_t)(0*Hq + J) * 128;
    const uint2* whh_o = w_hhT  + (size_t)(1*Hq + J) * 128;
    const uint2* whh_g = w_hhT  + (size_t)(2*Hq + J) * 128;
    const uint2* awhh  = aw_hhT + (size_t)J * 128;
    const uint2* wwh_f = ww_hhT + (size_t)(0*Hq + J) * 128;
    const uint2* wwh_i = ww_hhT + (size_t)(1*Hq + J) * 128;
    const uint2* wwh_g = ww_hhT + (size_t)(2*Hq + J) * 128;
#pragma unroll
    for (int it = 0; it < 8; ++it){
      const int q = it * 16 + lane;
      Rwhh_i[it] = whh_i[q];  Rwhh_o[it] = whh_o[q];  Rwhh_g[it] = whh_g[q];
      Rawhh[it]  = awhh[q];
      Rwwh_f[it] = wwh_f[q];  Rwwh_i[it] = wwh_i[q];  Rwwh_g[it] = wwh_g[q];
    }
    const uint2* wih_i = w_ihT  + (size_t)(0*Hq + J) * 32;
    const uint2* wih_o = w_ihT  + (size_t)(1*Hq + J) * 32;
    const uint2* wih_g = w_ihT  + (size_t)(2*Hq + J) * 32;
    const uint2* awih  = aw_ihT + (size_t)J * 32;
    const uint2* wwi_f = ww_ihT + (size_t)(0*Hq + J) * 32;
    const uint2* wwi_i = ww_ihT + (size_t)(1*Hq + J) * 32;
    const uint2* wwi_g = ww_ihT + (size_t)(2*Hq + J) * 32;
#pragma unroll
    for (int it = 0; it < 2; ++it){
      const int q = it * 16 + lane;
      Rwih_i[it] = wih_i[q];  Rwih_o[it] = wih_o[q];  Rwih_g[it] = wih_g[q];
      Rawih[it]  = awih[q];
      Rwwi_f[it] = wwi_f[q];  Rwwi_i[it] = wwi_i[q];  Rwwi_g[it] = wwi_g[q];
    }
  }

  const float b_i  = bias_b[J], b_o = bias_b[Hq + J], b_g = bias_b[2*Hq + J];
  const float ab_J = bias_ab[J];
  const float wb_f = bias_wb[J], wb_i = bias_wb[Hq + J], wb_g = bias_wb[2*Hq + J];

  float* out_h = out + (size_t)seq * Tq * Hq;            // hs block
  float* out_c = out + ((size_t)Bq + seq) * Tq * Hq;     // cs block

  __shared__ __align__(16) float shH[2][Hq];      // h by parity: shH[t&1] = h(t)
  __shared__ __align__(16) float sh_p0[Hq];
  __shared__ __align__(16) float sh_p1[Hq];
  __shared__ __align__(16) float shx[2][DCq];     // x(t) in shx[t&1]
  __shared__ __align__(16) float shxw0[2][DCq];   // xw(t) in shxw*[t&1]
  __shared__ __align__(16) float shxw1[2][DCq];

  // ---- pre-loop staging: zeros + x(0), xw(0) ----
  shH[0][i0] = 0.f; shH[0][i1] = 0.f;
  shH[1][i0] = 0.f; shH[1][i1] = 0.f;
  sh_p0[i0] = 0.f; sh_p0[i1] = 0.f;
  sh_p1[i0] = 0.f; sh_p1[i1] = 0.f;
  if (tid < DCq){
    shx[0][tid] = char_emb[((size_t)seq * Tq + 0) * DCq + tid];
  } else {
    const int k = tid - DCq;
    const int w0 = word_ids[(size_t)seq * Tq * 2 + 0];
    const int w1 = word_ids[(size_t)seq * Tq * 2 + 1];
    shxw0[0][k] = sense_table[(size_t)w0 * DCq + k];
    shxw1[0][k] = sense_table[(size_t)w1 * DCq + k];
  }
  __syncthreads();

  for (int t = 0; t < Tq; ++t){
    const int par = t & 1;
    const float* hprev = shH[par ^ 1];     // h(t-1)

    // pend poll pointers for this step
    const int slot = (t & 3) * 2;
    const u64* pf0 = pndf + (size_t)(slot + 0) * Hq;
    const u64* pf1 = pndf + (size_t)(slot + 1) * Hq;
    const u64* ps0 = pnds + (size_t)(slot + 0) * Hq;
    const u64* ps1 = pnds + (size_t)(slot + 1) * Hq;

    // ---- P0: early-issue slow pend loads (wait sinks below A1) ----
    u64 ea = 0, eb = 0, ec = 0, ed = 0;
    if (t >= 3){
      ea = ld64(ps0 + i0); eb = ld64(ps0 + i1);
      ec = ld64(ps1 + i0); ed = ld64(ps1 + i1);
    } else if (t >= 1){
      ea = ld64(ps0 + i0); eb = ld64(ps0 + i1);
    }

    // ---- A1: i/o/g/xa matvecs (pend NOT needed) ----
    float a_i = 0.f, a_o = 0.f, a_g = 0.f, a_xa = 0.f;
#pragma unroll
    for (int it = 0; it < 8; ++it){
      const int k0 = it * 64 + lane * 4;
      float4 hv = *(const float4*)(hprev + k0);
      fma4(a_i, Rwhh_i[it], hv);
      fma4(a_o, Rwhh_o[it], hv);
      fma4(a_g, Rwhh_g[it], hv);
    }
#pragma unroll
    for (int it = 0; it < 2; ++it){
      const int k0 = it * 64 + lane * 4;
      float4 xv = *(const float4*)(shx[par] + k0);
      fma4(a_i,  Rwih_i[it], xv);
      fma4(a_o,  Rwih_o[it], xv);
      fma4(a_g,  Rwih_g[it], xv);
      fma4(a_xa, Rawih[it],  xv);
    }

    // ---- A2: check early loads; else merged dual-scope spin ----
    if (t >= 3){
      const unsigned tg0 = (unsigned)t, tg1 = (unsigned)(t - 2);
      unsigned v00, v01, v10, v11;
      if (genof(ea) >= tg0 && genof(eb) >= tg0 &&
          genof(ec) >= tg1 && genof(ed) >= tg1){
        v00 = (unsigned)ea; v01 = (unsigned)eb;
        v10 = (unsigned)ec; v11 = (unsigned)ed;
      } else {
        for (;;){
          u32x4 f0, f1, s0, s1;
          quad_load(pf0 + i0, pf1 + i0, ps0 + i0, ps1 + i0, f0, f1, s0, s1);
          const bool k0f = f0.y >= tg0 && f0.w >= tg0;
          const bool k1f = f1.y >= tg1 && f1.w >= tg1;
          const bool k0s = s0.y >= tg0 && s0.w >= tg0;
          const bool k1s = s1.y >= tg1 && s1.w >= tg1;
          if ((k0f || k0s) && (k1f || k1s)){
            v00 = k0f ? f0.x : s0.x;  v01 = k0f ? f0.z : s0.z;
            v10 = k1f ? f1.x : s1.x;  v11 = k1f ? f1.z : s1.z;
            break;
          }
        }
      }
      sh_p0[i0] = __uint_as_float(v00); sh_p0[i1] = __uint_as_float(v01);
      sh_p1[i0] = __uint_as_float(v10); sh_p1[i1] = __uint_as_float(v11);
    } else if (t >= 1){
      const unsigned tg0 = (unsigned)t;
      unsigned v00, v01;
      if (genof(ea) >= tg0 && genof(eb) >= tg0){
        v00 = (unsigned)ea; v01 = (unsigned)eb;
      } else {
        for (;;){
          u32x4 f, s;
          duo_load(pf0 + i0, ps0 + i0, f, s);
          if (f.y >= tg0 && f.w >= tg0){ v00 = f.x; v01 = f.z; break; }
          if (s.y >= tg0 && s.w >= tg0){ v00 = s.x; v01 = s.z; break; }
        }
      }
      sh_p0[i0] = __uint_as_float(v00); sh_p0[i1] = __uint_as_float(v01);
      // sh_p1 stays zero (mask m1=0 for t<3)
    }
    __syncthreads();   // S1

    // ---- A3: alpha matvecs + gates ----
    float a_p0 = 0.f, a_p1 = 0.f;
#pragma unroll
    for (int it = 0; it < 8; ++it){
      const int k0 = it * 64 + lane * 4;
      float4 p0v = *(const float4*)(sh_p0 + k0);
      float4 p1v = *(const float4*)(sh_p1 + k0);
      fma4(a_p0, Rawhh[it], p0v);
      fma4(a_p1, Rawhh[it], p1v);
    }
    a_i  = red16(a_i);  a_o  = red16(a_o);  a_g  = red16(a_g);
    a_xa = red16(a_xa); a_p0 = red16(a_p0); a_p1 = red16(a_p1);

    const float gi = sigm(a_i + b_i);
    const float go = sigm(a_o + b_o);
    const float gg = tanhf(a_g + b_g);
    float c1;
    if (t == 0){
      c1 = gi * gg;                       // c_plain with c=0
    } else {
      const float base = a_xa + ab_J;
      const float ea0 = __expf(sigm(base + a_p0));   // m0=1 for t>=1
      const float ei  = __expf(gi);
      float num = ei * gg + ea0 * sh_p0[J];
      float den = ei + ea0;
      if (t >= 3){                                    // m1=1 for t>=3
        const float ea1 = __expf(sigm(base + a_p1));
        num += ea1 * sh_p1[J];
        den += ea1;
      }
      c1 = num / den;
    }
    const float h1 = go * tanhf(c1);
    if (lane == 0){
      const u64 pk = pack64(h1, (unsigned)(t + 1));
      *(volatile u64*)(hpubf + (size_t)par * Hq + J) = pk;  // plain: local L2
      pub64(hpubs + (size_t)par * Hq + J, pk);              // sc1: LLC
      out_h[(size_t)t * Hq + J] = h1;
      out_c[(size_t)t * Hq + J] = c1;
    }

    // ---- B2: early h loads + stage x/xw(t+1) + xw matvecs + poll h(t) ----
    float x_f0 = 0.f, x_i0 = 0.f, x_g0 = 0.f, x_f1 = 0.f, x_i1 = 0.f, x_g1 = 0.f;
    {
      const u64* hf = hpubf + (size_t)par * Hq;
      const u64* hs = hpubs + (size_t)par * Hq;
      const unsigned tg = (unsigned)(t + 1);
      // early-issue slow h loads (wait sinks below staging + matvecs)
      u64 ha = ld64(hs + i0), hb = ld64(hs + i1);

      const int tn = (t + 1 < Tq) ? t + 1 : t;
      if (tid < DCq){
        shx[par ^ 1][tid] = char_emb[((size_t)seq * Tq + tn) * DCq + tid];
      } else {
        const int k = tid - DCq;
        const int w0 = word_ids[((size_t)seq * Tq + tn) * 2 + 0];
        const int w1 = word_ids[((size_t)seq * Tq + tn) * 2 + 1];
        shxw0[par ^ 1][k] = sense_table[(size_t)w0 * DCq + k];
        shxw1[par ^ 1][k] = sense_table[(size_t)w1 * DCq + k];
      }
      // h-independent parts of the word gates (reads shxw*[par], written at t-1)
#pragma unroll
      for (int it = 0; it < 2; ++it){
        const int k0 = it * 64 + lane * 4;
        float4 x0 = *(const float4*)(shxw0[par] + k0);
        float4 x1 = *(const float4*)(shxw1[par] + k0);
        fma4(x_f0, Rwwi_f[it], x0);  fma4(x_f1, Rwwi_f[it], x1);
        fma4(x_i0, Rwwi_i[it], x0);  fma4(x_i1, Rwwi_i[it], x1);
        fma4(x_g0, Rwwi_g[it], x0);  fma4(x_g1, Rwwi_g[it], x1);
      }
      x_f0 = red16(x_f0); x_i0 = red16(x_i0); x_g0 = red16(x_g0);
      x_f1 = red16(x_f1); x_i1 = red16(x_i1); x_g1 = red16(x_g1);

      // poll full h(t) — the ONE exposed round trip
      unsigned va, vb;
      if (genof(ha) >= tg && genof(hb) >= tg){
        va = (unsigned)ha; vb = (unsigned)hb;
      } else {
        for (;;){
          u32x4 f, s;
          duo_load(hf + i0, hs + i0, f, s);
          if (f.y >= tg && f.w >= tg){ va = f.x; vb = f.z; break; }
          if (s.y >= tg && s.w >= tg){ va = s.x; vb = s.z; break; }
        }
      }
      shH[par][i0] = __uint_as_float(va); shH[par][i1] = __uint_as_float(vb);
    }
    __syncthreads();   // S2

    // ---- B3: h-dependent word gates ----
    float r_f = 0.f, r_i = 0.f, r_g = 0.f;
#pragma unroll
    for (int it = 0; it < 8; ++it){
      const int k0 = it * 64 + lane * 4;
      float4 hv = *(const float4*)(shH[par] + k0);
      fma4(r_f, Rwwh_f[it], hv);
      fma4(r_i, Rwwh_i[it], hv);
      fma4(r_g, Rwwh_g[it], hv);
    }
    r_f = red16(r_f);  r_i = red16(r_i);  r_g = red16(r_g);

    if (lane == 0){
      const float f0  = sigm(r_f + x_f0 + wb_f);
      const float iw0 = sigm(r_i + x_i0 + wb_i);
      const float g0  = tanhf(r_g + x_g0 + wb_g);
      const float cw0 = f0 * c1 + iw0 * g0;
      const float f1  = sigm(r_f + x_f1 + wb_f);
      const float iw1 = sigm(r_i + x_i1 + wb_i);
      const float g1  = tanhf(r_g + x_g1 + wb_g);
      const float cw1 = f1 * c1 + iw1 * g1;
      // gen = production step + 1; consumers poll p0>=t_c, p1>=t_c-2
      const u64 pk0 = pack64(cw0, (unsigned)(t + 1));
      const u64 pk1 = pack64(cw1, (unsigned)(t + 1));
      const size_t o0 = ((size_t)((t + 1) & 3) * 2 + 0) * Hq + J;
      const size_t o1 = ((size_t)((t + 3) & 3) * 2 + 1) * Hq + J;
      *(volatile u64*)(pndf + o0) = pk0;   // plain: local L2
      *(volatile u64*)(pndf + o1) = pk1;
      pub64(pnds + o0, pk0);               // sc1: LLC
      pub64(pnds + o1, pk1);
    }
    // no barrier here: next A1 touches only shH[par^1]/shx[par^1] (disjoint),
    // next A2 LDS writes are fenced by S1; pend LDS buffers re-written only
    // after S2 of this step (cross-thread ordering via S1/S2 chain).
  }
}

extern "C" void kernel_launch(void* const* d_in, const int* in_sizes, int n_in,
                              void* d_out, int out_size, void* d_ws, size_t ws_size,
                              hipStream_t stream){
  const float* char_emb = (const float*)d_in[0];
  const int*   word_ids = (const int*)d_in[1];
  const float* sense    = (const float*)d_in[2];
  const float* w_ih     = (const float*)d_in[3];
  const float* w_hh     = (const float*)d_in[4];
  const float* bb       = (const float*)d_in[5];
  const float* aw_ih    = (const float*)d_in[6];
  const float* aw_hh    = (const float*)d_in[7];
  const float* ab       = (const float*)d_in[8];
  const float* ww_ih    = (const float*)d_in[9];
  const float* ww_hh    = (const float*)d_in[10];
  const float* wb       = (const float*)d_in[11];
  unsigned char* ws = (unsigned char*)d_ws;
  float* out = (float*)d_out;

  // zero all generation words (h_pub/pend, fast+slow)
  hipMemsetAsync(ws, 0, WIHT_OFF, stream);

  // one-time (per launch) weight convert+transpose to bf16
  transpose_bf16<<<512, NTHR, 0, stream>>>(w_ih,  (__hip_bfloat16*)(ws + WIHT_OFF),  7, 128*1536, 1536);
  transpose_bf16<<<512, NTHR, 0, stream>>>(w_hh,  (__hip_bfloat16*)(ws + WHHT_OFF),  9, 512*1536, 1536);
  transpose_bf16<<<512, NTHR, 0, stream>>>(aw_ih, (__hip_bfloat16*)(ws + AWIHT_OFF), 7, 128*512,  512);
  transpose_bf16<<<512, NTHR, 0, stream>>>(aw_hh, (__hip_bfloat16*)(ws + AWHHT_OFF), 9, 512*512,  512);
  transpose_bf16<<<512, NTHR, 0, stream>>>(ww_ih, (__hip_bfloat16*)(ws + WWIHT_OFF), 7, 128*1536, 1536);
  transpose_bf16<<<512, NTHR, 0, stream>>>(ww_hh, (__hip_bfloat16*)(ws + WWHHT_OFF), 9, 512*1536, 1536);

  dim3 grid(Bq, NWG);   // x = seq (XCD-local: linear id % 8 == seq), y = wg slice
  lattice_main<<<grid, NTHR, 0, stream>>>(char_emb, word_ids, sense, bb, ab, wb, ws, out);
}